// Round 5
// baseline (448.308 us; speedup 1.0000x reference)
//
#include <hip/hip_runtime.h>
#include <hip/hip_bf16.h>

// LengthRegulator: B=32, T=1024, D=384, MAX_LEN=8192
// out0: (B, MAX_LEN, D) f32 gather of x rows per searchsorted(cumsum(duration), frame, 'right')
// out1: (B,) mel_len = cumsum(duration)[:, -1], stored as float values in d_out tail.
//
// Traffic floor: 402.7 MB out-write + ~55 MB x-read ≈ 457 MB → ~73 us @ 6.3 TB/s.
// dur_us additionally contains fixed harness work (1.5 GiB ws poison fill ~255 us,
// d_out fill ~64 us, input restores) per timed iteration.

#define LR_B 32
#define LR_T 1024
#define LR_D 384
#define LR_MAXLEN 8192
#define LR_D4 (LR_D / 4)                  // 96 float4 per row
#define LR_N4 (LR_B * LR_MAXLEN * LR_D4)  // 25,165,824 float4 in out0
#define LR_UNROLL 16

typedef float fx4 __attribute__((ext_vector_type(4)));

// Kernel A: per-batch inclusive scan of durations via wave shuffles (2 barriers
// total). Emits mel_len (float-coded) and a frame -> source-offset table:
//   src_ws[b*MAX_LEN + f] = (b*T + token)*D4   for valid frames
//                         = -1                  for frames >= mel_len
__global__ __launch_bounds__(LR_T) void lr_scan_scatter(
    const int* __restrict__ dur,     // (B, T)
    int* __restrict__ src_ws,        // (B, MAX_LEN)
    float* __restrict__ mel_out)     // (B,) float-coded int
{
    const int b = blockIdx.x;
    const int t = threadIdx.x;
    const int lane = t & 63;
    const int wave = t >> 6;         // 16 waves

    const int d = dur[b * LR_T + t];

    // Inclusive scan within the wave (6 shuffle steps, no barriers)
    int v = d;
    #pragma unroll
    for (int off = 1; off < 64; off <<= 1) {
        int n = __shfl_up(v, off, 64);
        if (lane >= off) v += n;
    }

    __shared__ int wsum[16];
    __shared__ int woff[16];
    if (lane == 63) wsum[wave] = v;
    __syncthreads();

    // Scan the 16 wave sums inside wave 0
    if (wave == 0 && lane < 16) {
        int s = wsum[lane];
        #pragma unroll
        for (int off = 1; off < 16; off <<= 1) {
            int n = __shfl_up(s, off, 64);
            if (lane >= off) s += n;
        }
        woff[lane] = s;              // inclusive scan of wave sums
    }
    __syncthreads();

    const int base  = (wave == 0) ? 0 : woff[wave - 1];
    const int end   = base + v;      // inclusive csum at token t
    const int start = end - d;
    const int total = woff[15];      // mel_len, <= 7*1024 < MAX_LEN

    if (t == 0) mel_out[b] = (float)total;

    int* row = src_ws + b * LR_MAXLEN;
    const int src_off = (b * LR_T + t) * LR_D4;   // float4 offset of token row
    for (int f = start; f < end; ++f) row[f] = src_off;   // <= 7 iterations
    for (int f = total + t; f < LR_MAXLEN; f += LR_T) row[f] = -1;
}

// Kernel B: 16 float4 copies per thread (256 B), XCD-swizzled block order so
// each XCD's L2 sees a contiguous 1/8 of the frame range (x working set
// ~6 MB/XCD). Decisive probe: if this is neutral, the gather is write-BW
// bound at floor.
__global__ __launch_bounds__(256) void lr_gather(
    const fx4* __restrict__ x,       // (B, T, D4)
    const int* __restrict__ src_ws,  // (B, MAX_LEN)
    fx4* __restrict__ out)           // (B, MAX_LEN, D4)
{
    // blocks dispatch round-robin over 8 XCDs: hw block i -> XCD i%8.
    // Remap so XCD j owns logical blocks [j*nb/8, (j+1)*nb/8).
    const unsigned nb8 = gridDim.x >> 3;
    const unsigned lb = (blockIdx.x & 7u) * nb8 + (blockIdx.x >> 3);

    const unsigned base = lb * (256u * LR_UNROLL) + threadIdx.x;
    #pragma unroll
    for (int u = 0; u < LR_UNROLL; ++u) {
        const unsigned g = base + u * 256u;          // < LR_N4 exactly
        const unsigned frame = g / LR_D4;            // magic-mul div by 96
        const unsigned e = g - frame * LR_D4;
        const int s = src_ws[frame];                 // L1 broadcast (96 threads/line share)
        fx4 v = (fx4)0.f;
        if (s >= 0) v = x[(unsigned)s + e];
        out[g] = v;
    }
}

extern "C" void kernel_launch(void* const* d_in, const int* in_sizes, int n_in,
                              void* d_out, int out_size, void* d_ws, size_t ws_size,
                              hipStream_t stream) {
    const float* x   = (const float*)d_in[0];
    const int*   dur = (const int*)d_in[1];
    // d_in[2] = max_len (scalar on device) -- constant 8192 for this problem.

    float* out0 = (float*)d_out;                          // (B, MAX_LEN, D)
    float* mel  = out0 + (size_t)LR_B * LR_MAXLEN * LR_D; // (B,) tail
    int*   src_ws = (int*)d_ws;                           // B*MAX_LEN ints = 1 MB

    lr_scan_scatter<<<LR_B, LR_T, 0, stream>>>(dur, src_ws, mel);

    const int n_blocks = LR_N4 / (256 * LR_UNROLL);       // 6144, exact; /8 = 768
    lr_gather<<<n_blocks, 256, 0, stream>>>(
        (const fx4*)x, src_ws, (fx4*)out0);
}